// Round 1
// baseline (89342.645 us; speedup 1.0000x reference)
//
#include <hip/hip_runtime.h>

// Problem dims
#define T_ 128
#define B_ 64
#define E_ 256
#define H_ 512
#define S_ 1024
#define G_ 2048           // 4H
#define NCH 6             // attention s-chunks per batch row
#define NBLK 512
#define ABLK 128          // blocks doing LSTM (A) + output heads (C)
#define BLK 256

// ws layout (float indices); bytes 0..7 = barrier {cnt, gen}
#define F_V1   256                      // 512: Wpg[0:512] + Wax_top @ w4
#define F_VX   (F_V1 + H_)              // 256: Wax_bot @ w4
#define F_S0   (F_VX + E_)              // 1:   b_pg + b_ax . w4
#define F_BIAS (F_S0 + 64)              // B*S: 0 or -inf mask bias
#define F_H3   (F_BIAS + B_*S_)         // 3 * B*H  (h_t stored at slot t%3; h0 at slot 2)
#define F_C3   (F_H3 + 3*B_*H_)         // 3 * B*H
#define F_SC2  (F_C3 + 3*B_*H_)         // 2 * B*S raw scores (double buffer)
#define PSTR   520
#define F_PART (F_SC2 + 2*B_*S_)        // 2 * B*NCH*PSTR partials {m,l,pad,ctx[512]}
#define F_TOTAL (F_PART + 2*B_*NCH*PSTR)

// out layout (float indices)
#define O_OUT 0
#define O_H   ((size_t)T_*B_*H_)
#define O_C   (O_H + B_*H_)
#define O_AD  (O_C + B_*H_)
#define O_PG  (O_AD + (size_t)T_*B_*S_)

#define NEG_INF (-__builtin_inff())

__device__ __forceinline__ float sigm(float x){ return 1.f/(1.f+__expf(-x)); }
__device__ __forceinline__ float tanh_(float x){ return 1.f - 2.f/(1.f+__expf(2.f*x)); }
__device__ __forceinline__ float wred(float v){
#pragma unroll
  for (int m = 1; m < 64; m <<= 1) v += __shfl_xor(v, m, 64);
  return v;
}

// device-scope grid barrier (all NBLK blocks co-resident by construction)
__device__ __forceinline__ void gbar(unsigned* bar){
  __syncthreads();
  if (threadIdx.x == 0) {
    __threadfence();
    unsigned g = __hip_atomic_load(&bar[1], __ATOMIC_RELAXED, __HIP_MEMORY_SCOPE_AGENT);
    unsigned a = __hip_atomic_fetch_add(&bar[0], 1u, __ATOMIC_ACQ_REL, __HIP_MEMORY_SCOPE_AGENT);
    if (a == NBLK - 1u) {
      __hip_atomic_store(&bar[0], 0u, __ATOMIC_RELAXED, __HIP_MEMORY_SCOPE_AGENT);
      __hip_atomic_store(&bar[1], g + 1u, __ATOMIC_RELEASE, __HIP_MEMORY_SCOPE_AGENT);
    } else {
      while (__hip_atomic_load(&bar[1], __ATOMIC_ACQUIRE, __HIP_MEMORY_SCOPE_AGENT) == g)
        __builtin_amdgcn_s_sleep(4);
    }
    __threadfence();
  }
  __syncthreads();
}

// ---------------- Phase A: LSTM cell for step t ----------------
// blocks [0,ABLK): block owns 4 hidden units x all 64 batch rows; 1 cell/thread.
__device__ void do_A(int t, int bid, int tid,
                     const float* __restrict__ emb, const float* __restrict__ Wih,
                     const float* __restrict__ bih, const float* __restrict__ Whh,
                     const float* __restrict__ bhh, float* __restrict__ F)
{
  const int b = tid >> 2, ul = tid & 3, u = bid*4 + ul;
  const float* hb = F + F_H3 + ((t+2)%3)*(B_*H_) + b*H_;   // h_{t-1}
  const float* cb = F + F_C3 + ((t+2)%3)*(B_*H_) + b*H_;   // c_{t-1}
  float ai = bih[u]      + bhh[u];
  float af = bih[u+512]  + bhh[u+512];
  float ag = bih[u+1024] + bhh[u+1024];
  float ao = bih[u+1536] + bhh[u+1536];
  const float* xr = emb + ((size_t)b*T_ + t)*E_;           // emb is [B,T,E]
  const float* w = Wih + u;
#pragma unroll 4
  for (int k = 0; k < E_; ++k) {
    float xv = xr[k];
    ai = fmaf(xv, w[0], ai);    af = fmaf(xv, w[512], af);
    ag = fmaf(xv, w[1024], ag); ao = fmaf(xv, w[1536], ao);
    w += G_;
  }
  w = Whh + u;
#pragma unroll 4
  for (int k = 0; k < H_; ++k) {
    float hv = hb[k];
    ai = fmaf(hv, w[0], ai);    af = fmaf(hv, w[512], af);
    ag = fmaf(hv, w[1024], ag); ao = fmaf(hv, w[1536], ao);
    w += G_;
  }
  float cn = sigm(af)*cb[u] + sigm(ai)*tanh_(ag);
  float hn = sigm(ao)*tanh_(cn);
  F[F_H3 + (t%3)*(B_*H_) + b*H_ + u] = hn;
  F[F_C3 + (t%3)*(B_*H_) + b*H_ + u] = cn;
}

// ---------------- Phase B: single-pass attention partials for step t ----------------
// blocks [ABLK,NBLK): block owns (b, chunk). Online softmax into regs; partial out to ws.
__device__ void do_B(int t, int bid, int tid, const float* __restrict__ ctx,
                     float* __restrict__ F, float (*s_red)[H_+8], float* s_ml)
{
  const int idx = bid - ABLK;
  const int b = idx / NCH, ch = idx - b*NCH;
  const int sb = (ch*S_)/NCH, se = ((ch+1)*S_)/NCH;
  const int w = tid >> 6, lane = tid & 63;
  const float* hb = F + F_H3 + (t%3)*(B_*H_) + b*H_ + lane*8;
  const float4 hA = *(const float4*)hb;
  const float4 hB = *(const float4*)(hb + 4);
  const float* bias = F + F_BIAS + b*S_;
  float* scw = F + F_SC2 + (size_t)(t&1)*(B_*S_) + b*S_;
  float m = NEG_INF, l = 0.f;
  float a0=0,a1=0,a2=0,a3=0,a4=0,a5=0,a6=0,a7=0;
  for (int s = sb + w; s < se; s += 4) {
    const float* cr = ctx + ((size_t)b*S_ + s)*H_ + lane*8;
    float4 cA = *(const float4*)cr;
    float4 cB = *(const float4*)(cr + 4);
    float d = cA.x*hA.x + cA.y*hA.y + cA.z*hA.z + cA.w*hA.w
            + cB.x*hB.x + cB.y*hB.y + cB.z*hB.z + cB.w*hB.w;
    d = wred(d);
    float sc = d + bias[s];
    if (lane == 0) scw[s] = sc;
    float mn = fmaxf(m, sc);
    float al = (mn == m) ? 1.f : __expf(m - mn);
    float wg = (sc == NEG_INF) ? 0.f : __expf(sc - mn);
    l = l*al + wg;
    a0 = a0*al + wg*cA.x; a1 = a1*al + wg*cA.y;
    a2 = a2*al + wg*cA.z; a3 = a3*al + wg*cA.w;
    a4 = a4*al + wg*cB.x; a5 = a5*al + wg*cB.y;
    a6 = a6*al + wg*cB.z; a7 = a7*al + wg*cB.w;
    m = mn;
  }
  if (lane == 0) { s_ml[w*2] = m; s_ml[w*2+1] = l; }
  { float* r = s_red[w] + lane*8;
    r[0]=a0; r[1]=a1; r[2]=a2; r[3]=a3; r[4]=a4; r[5]=a5; r[6]=a6; r[7]=a7; }
  __syncthreads();
  float m0=s_ml[0], l0=s_ml[1], m1=s_ml[2], l1=s_ml[3],
        m2=s_ml[4], l2=s_ml[5], m3=s_ml[6], l3=s_ml[7];
  float mb = fmaxf(fmaxf(m0,m1), fmaxf(m2,m3));
  float k0 = (l0>0.f) ? __expf(m0-mb) : 0.f;
  float k1 = (l1>0.f) ? __expf(m1-mb) : 0.f;
  float k2 = (l2>0.f) ? __expf(m2-mb) : 0.f;
  float k3 = (l3>0.f) ? __expf(m3-mb) : 0.f;
  float lb = k0*l0 + k1*l1 + k2*l2 + k3*l3;
  float* Pp = F + F_PART + (size_t)(t&1)*(B_*NCH*PSTR) + (size_t)(b*NCH+ch)*PSTR;
  for (int u = tid; u < H_; u += BLK)
    Pp[8+u] = k0*s_red[0][u] + k1*s_red[1][u] + k2*s_red[2][u] + k3*s_red[3][u];
  if (tid == 0) { Pp[0] = mb; Pp[1] = lb; }
}

// ---------------- Phase C: outputs for step tc ----------------
// blocks [0,ABLK): (b = bid>>1, p = bid&1). Merge partials -> attn_ctx; write
// attn_dist, out row slice, p_gen.
__device__ void do_C(int tc, int bid, int tid,
                     const float* __restrict__ emb, const float* __restrict__ Wout,
                     const float* __restrict__ bout, const float* __restrict__ Wpg,
                     float* __restrict__ out, float* __restrict__ F,
                     float* s_actx, float* s_tmp)
{
  const int b = bid >> 1, p = bid & 1;
  const float* P0 = F + F_PART + (size_t)(tc&1)*(B_*NCH*PSTR) + (size_t)(b*NCH)*PSTR;
  float mk[NCH], lk[NCH], ck[NCH];
  float mb = NEG_INF;
#pragma unroll
  for (int k = 0; k < NCH; ++k) { mk[k]=P0[k*PSTR]; lk[k]=P0[k*PSTR+1]; mb=fmaxf(mb,mk[k]); }
  float lb = 0.f;
#pragma unroll
  for (int k = 0; k < NCH; ++k) { ck[k] = (lk[k]>0.f) ? __expf(mk[k]-mb) : 0.f; lb += ck[k]*lk[k]; }
  float inv = 1.f/lb;
  for (int u = tid; u < H_; u += BLK) {
    float v = 0.f;
#pragma unroll
    for (int k = 0; k < NCH; ++k) v += ck[k]*P0[k*PSTR+8+u];
    s_actx[u] = v*inv;
  }
  __syncthreads();
  { // attention distribution
    const float* scr = F + F_SC2 + (size_t)(tc&1)*(B_*S_) + b*S_;
    float* ad = out + O_AD + ((size_t)tc*B_ + b)*S_;
    int s = p*512 + tid;
    ad[s] = __expf(scr[s]-mb)*inv;
    s += 256;
    ad[s] = __expf(scr[s]-mb)*inv;
  }
  const float* hb = F + F_H3 + (tc%3)*(B_*H_) + b*H_;
  { // out = [attn_ctx, h] @ W_out + b_out
    int j = p*256 + tid;
    float acc = bout[j];
    const float* wq = Wout + j;
    for (int k = 0; k < H_; ++k) { acc = fmaf(s_actx[k], wq[0], acc); wq += H_; }
    for (int k = 0; k < H_; ++k) { acc = fmaf(hb[k],     wq[0], acc); wq += H_; }
    out[O_OUT + ((size_t)tc*B_ + b)*H_ + j] = acc;
  }
  if (p == 0) { // p_gen via folded dot products
    const float* cb = F + F_C3 + (tc%3)*(B_*H_) + b*H_;
    const float* xr = emb + ((size_t)b*T_ + tc)*E_;
    float part = 0.f;
    for (int i = tid; i < 1792; i += BLK) {
      float v;
      if (i < 512)       v = s_actx[i]   * F[F_V1 + i];
      else if (i < 1024) v = hb[i-512]   * Wpg[i];
      else if (i < 1536) v = cb[i-1024]  * Wpg[i];
      else               v = xr[i-1536]  * F[F_VX + i - 1536];
      part += v;
    }
    part = wred(part);
    if ((tid & 63) == 0) s_tmp[tid>>6] = part;
    __syncthreads();
    if (tid == 0)
      out[O_PG + (size_t)tc*B_ + b] = sigm(s_tmp[0]+s_tmp[1]+s_tmp[2]+s_tmp[3] + F[F_S0]);
  }
}

__global__ __launch_bounds__(BLK, 2)
void decoder_kernel(const float* __restrict__ emb, const float* __restrict__ h0,
                    const float* __restrict__ c0, const float* __restrict__ ctx,
                    const float* __restrict__ Wih, const float* __restrict__ bih,
                    const float* __restrict__ Whh, const float* __restrict__ bhh,
                    const float* __restrict__ Wout, const float* __restrict__ bout,
                    const float* __restrict__ Wax, const float* __restrict__ bax,
                    const float* __restrict__ Wpg, const float* __restrict__ bpg,
                    float* __restrict__ out, float* __restrict__ F)
{
  __shared__ float s_red[4][H_+8];
  __shared__ float s_ml[8];
  __shared__ float s_actx[H_];
  __shared__ float s_tmp[4];
  unsigned* bar = (unsigned*)F;
  const int tid = threadIdx.x, bid = blockIdx.x;

  // ---- phase 0: init state, mask bias, p_gen folds ----
  { int i = bid*BLK + tid;
    if (i < B_*H_) { F[F_H3 + 2*(B_*H_) + i] = h0[i]; F[F_C3 + 2*(B_*H_) + i] = c0[i]; } }
  { const int w = tid>>6, lane = tid&63;
    for (int rr = 0; rr < 32; ++rr) {
      int row = bid*128 + rr*4 + w;                       // row = b*S + s
      const float* cr = ctx + (size_t)row*H_ + lane*8;
      float4 cA = *(const float4*)cr, cB = *(const float4*)(cr+4);
      float ssum = cA.x+cA.y+cA.z+cA.w+cB.x+cB.y+cB.z+cB.w;
      ssum = wred(ssum);
      if (lane == 0) F[F_BIAS + row] = (ssum == 0.f) ? NEG_INF : 0.f;
    } }
  if (bid < 5) {
    const int w = tid>>6, lane = tid&63;
    const float* wp = Wpg + 1536 + lane*8;
    float4 wA = *(const float4*)wp, wB = *(const float4*)(wp+4);
    if (bid < 4) {
      for (int rr = 0; rr < 32; ++rr) {
        int k = bid*128 + rr*4 + w;
        const float* ar = Wax + (size_t)k*H_ + lane*8;
        float4 xA = *(const float4*)ar, xB = *(const float4*)(ar+4);
        float d = xA.x*wA.x+xA.y*wA.y+xA.z*wA.z+xA.w*wA.w
                + xB.x*wB.x+xB.y*wB.y+xB.z*wB.z+xB.w*wB.w;
        d = wred(d);
        if (lane == 0) F[F_V1 + k] = Wpg[k] + d;
      }
    } else {
      for (int rr = 0; rr < 64; ++rr) {
        int k = rr*4 + w;
        const float* ar = Wax + (size_t)(512+k)*H_ + lane*8;
        float4 xA = *(const float4*)ar, xB = *(const float4*)(ar+4);
        float d = xA.x*wA.x+xA.y*wA.y+xA.z*wA.z+xA.w*wA.w
                + xB.x*wB.x+xB.y*wB.y+xB.z*wB.z+xB.w*wB.w;
        d = wred(d);
        if (lane == 0) F[F_VX + k] = d;
      }
      if (tid < 64) {
        const float* br = bax + lane*8;
        float4 bA = *(const float4*)br, bB = *(const float4*)(br+4);
        float d = bA.x*wA.x+bA.y*wA.y+bA.z*wA.z+bA.w*wA.w
                + bB.x*wB.x+bB.y*wB.y+bB.z*wB.z+bB.w*wB.w;
        d = wred(d);
        if (lane == 0) F[F_S0] = bpg[0] + d;
      }
    }
  }
  gbar(bar);

  // ---- prologue: A_0 ----
  if (bid < ABLK) do_A(0, bid, tid, emb, Wih, bih, Whh, bhh, F);
  gbar(bar);

  // ---- main loop: one barrier per step; B_t || A_{t+1} || C_{t-1} ----
  for (int t = 0; t < T_; ++t) {
    if (bid >= ABLK) {
      do_B(t, bid, tid, ctx, F, s_red, s_ml);
    } else {
      if (t < T_-1) do_A(t+1, bid, tid, emb, Wih, bih, Whh, bhh, F);
      if (t > 0)    do_C(t-1, bid, tid, emb, Wout, bout, Wpg, out, F, s_actx, s_tmp);
    }
    gbar(bar);
  }

  // ---- epilogue: C_{T-1} + final h,c  (h_127 lives in slot 127%3 == 1) ----
  if (bid < ABLK) {
    do_C(T_-1, bid, tid, emb, Wout, bout, Wpg, out, F, s_actx, s_tmp);
  } else {
    for (int i = (bid-ABLK)*BLK + tid; i < B_*H_; i += (NBLK-ABLK)*BLK) {
      out[O_H + i] = F[F_H3 + 1*(B_*H_) + i];
      out[O_C + i] = F[F_C3 + 1*(B_*H_) + i];
    }
  }
}

extern "C" void kernel_launch(void* const* d_in, const int* in_sizes, int n_in,
                              void* d_out, int out_size, void* d_ws, size_t ws_size,
                              hipStream_t stream)
{
  if (ws_size < (size_t)F_TOTAL * sizeof(float)) return;  // loud failure, no corruption
  hipMemsetAsync(d_ws, 0, 256, stream);                    // reset barrier each call
  decoder_kernel<<<dim3(NBLK), dim3(BLK), 0, stream>>>(
      (const float*)d_in[0],  (const float*)d_in[1],  (const float*)d_in[2],
      (const float*)d_in[3],  (const float*)d_in[4],  (const float*)d_in[5],
      (const float*)d_in[6],  (const float*)d_in[7],  (const float*)d_in[8],
      (const float*)d_in[9],  (const float*)d_in[10], (const float*)d_in[11],
      (const float*)d_in[12], (const float*)d_in[13],
      (float*)d_out, (float*)d_ws);
}

// Round 2
// 17127.246 us; speedup vs baseline: 5.2164x; 5.2164x over previous
//
#include <hip/hip_runtime.h>

// Problem dims
#define T_ 128
#define B_ 64
#define E_ 256
#define H_ 512
#define S_ 1024
#define G_ 2048           // 4H
#define NCH 6             // attention s-chunks per batch row
#define NBLK 512
#define ABLK 128          // blocks doing LSTM (A) + output heads (C)
#define BLK 256
#define NGRP 8            // broadcast "go" lines

// ---- barrier area (uint indices into ws) ----
// go[g] at W[g*16], g in [0,8)           : 8 lines
// arrive[bid] at W[128 + bid*16]         : 512 lines
#define U_ARR   128
#define U_TOTAL (U_ARR + NBLK*16)          // 8320 uints = 33280 B

// ws layout (float indices)
#define F_V1   8704                     // 512: Wpg[0:512] + Wax_top @ w4
#define F_VX   (F_V1 + H_)              // 256: Wax_bot @ w4
#define F_S0   (F_VX + E_)              // 1:   b_pg + b_ax . w4
#define F_BIAS (F_S0 + 64)              // B*S: 0 or -inf mask bias
#define F_H3   (F_BIAS + B_*S_)         // 3 * B*H  (h_t stored at slot t%3; h0 at slot 2)
#define F_C3   (F_H3 + 3*B_*H_)         // 3 * B*H
#define F_SC2  (F_C3 + 3*B_*H_)         // 2 * B*S raw scores (double buffer)
#define PSTR   520
#define F_PART (F_SC2 + 2*B_*S_)        // 2 * B*NCH*PSTR partials {m,l,pad,ctx[512]}
#define F_TOTAL (F_PART + 2*B_*NCH*PSTR)

// out layout (float indices)
#define O_OUT 0
#define O_H   ((size_t)T_*B_*H_)
#define O_C   (O_H + B_*H_)
#define O_AD  (O_C + B_*H_)
#define O_PG  (O_AD + (size_t)T_*B_*S_)

#define NEG_INF (-__builtin_inff())

__device__ __forceinline__ float sigm(float x){ return 1.f/(1.f+__expf(-x)); }
__device__ __forceinline__ float tanh_(float x){ return 1.f - 2.f/(1.f+__expf(2.f*x)); }
__device__ __forceinline__ float wred(float v){
#pragma unroll
  for (int m = 1; m < 64; m <<= 1) v += __shfl_xor(v, m, 64);
  return v;
}

// ---- contention-free grid barrier ----
// arrival: parallel relaxed stores (own cacheline per block). gather: block 0's
// 256 threads poll 2 slots each in parallel. broadcast: 8 spaced go-lines.
// exactly one release fence (producer side) + one acquire fence (consumer side)
// per block per barrier.
__device__ __forceinline__ void gbar(unsigned* W, unsigned ep){
  __syncthreads();                      // all block writes complete (vmcnt(0) before s_barrier)
  const int tid = threadIdx.x, bid = blockIdx.x;
  if (tid == 0) {
    __builtin_amdgcn_fence(__ATOMIC_RELEASE, "agent");   // flush this XCD's L2 once
    __hip_atomic_store(&W[U_ARR + bid*16], ep, __ATOMIC_RELAXED, __HIP_MEMORY_SCOPE_AGENT);
  }
  if (bid == 0) {
    const int i0 = tid*2, i1 = i0+1;
    while (__hip_atomic_load(&W[U_ARR + i0*16], __ATOMIC_RELAXED, __HIP_MEMORY_SCOPE_AGENT) < ep)
      __builtin_amdgcn_s_sleep(1);
    while (__hip_atomic_load(&W[U_ARR + i1*16], __ATOMIC_RELAXED, __HIP_MEMORY_SCOPE_AGENT) < ep)
      __builtin_amdgcn_s_sleep(1);
    __syncthreads();
    if (tid < NGRP)
      __hip_atomic_store(&W[tid*16], ep, __ATOMIC_RELAXED, __HIP_MEMORY_SCOPE_AGENT);
  }
  if (tid == 0) {
    while (__hip_atomic_load(&W[(bid>>6)*16], __ATOMIC_RELAXED, __HIP_MEMORY_SCOPE_AGENT) < ep)
      __builtin_amdgcn_s_sleep(2);
    __builtin_amdgcn_fence(__ATOMIC_ACQUIRE, "agent");   // invalidate stale L1/L2 once
  }
  __syncthreads();
}

// ---------------- Phase A: LSTM cell for step t ----------------
// blocks [0,ABLK): block owns 4 hidden units x all 64 batch rows; 1 cell/thread.
__device__ void do_A(int t, int bid, int tid,
                     const float* __restrict__ emb, const float* __restrict__ Wih,
                     const float* __restrict__ bih, const float* __restrict__ Whh,
                     const float* __restrict__ bhh, float* __restrict__ F)
{
  const int b = tid >> 2, ul = tid & 3, u = bid*4 + ul;
  const float* hb = F + F_H3 + ((t+2)%3)*(B_*H_) + b*H_;   // h_{t-1}
  const float* cb = F + F_C3 + ((t+2)%3)*(B_*H_) + b*H_;   // c_{t-1}
  float ai = bih[u]      + bhh[u];
  float af = bih[u+512]  + bhh[u+512];
  float ag = bih[u+1024] + bhh[u+1024];
  float ao = bih[u+1536] + bhh[u+1536];
  const float* xr = emb + ((size_t)b*T_ + t)*E_;           // emb is [B,T,E]
  const float* w = Wih + u;
#pragma unroll 4
  for (int k = 0; k < E_; ++k) {
    float xv = xr[k];
    ai = fmaf(xv, w[0], ai);    af = fmaf(xv, w[512], af);
    ag = fmaf(xv, w[1024], ag); ao = fmaf(xv, w[1536], ao);
    w += G_;
  }
  w = Whh + u;
#pragma unroll 4
  for (int k = 0; k < H_; ++k) {
    float hv = hb[k];
    ai = fmaf(hv, w[0], ai);    af = fmaf(hv, w[512], af);
    ag = fmaf(hv, w[1024], ag); ao = fmaf(hv, w[1536], ao);
    w += G_;
  }
  float cn = sigm(af)*cb[u] + sigm(ai)*tanh_(ag);
  float hn = sigm(ao)*tanh_(cn);
  F[F_H3 + (t%3)*(B_*H_) + b*H_ + u] = hn;
  F[F_C3 + (t%3)*(B_*H_) + b*H_ + u] = cn;
}

// ---------------- Phase B: single-pass attention partials for step t ----------------
// blocks [ABLK,NBLK): block owns (b, chunk). Online softmax into regs; partial out to ws.
__device__ void do_B(int t, int bid, int tid, const float* __restrict__ ctx,
                     float* __restrict__ F, float (*s_red)[H_+8], float* s_ml)
{
  const int idx = bid - ABLK;
  const int b = idx / NCH, ch = idx - b*NCH;
  const int sb = (ch*S_)/NCH, se = ((ch+1)*S_)/NCH;
  const int w = tid >> 6, lane = tid & 63;
  const float* hb = F + F_H3 + (t%3)*(B_*H_) + b*H_ + lane*8;
  const float4 hA = *(const float4*)hb;
  const float4 hB = *(const float4*)(hb + 4);
  const float* bias = F + F_BIAS + b*S_;
  float* scw = F + F_SC2 + (size_t)(t&1)*(B_*S_) + b*S_;
  float m = NEG_INF, l = 0.f;
  float a0=0,a1=0,a2=0,a3=0,a4=0,a5=0,a6=0,a7=0;
  for (int s = sb + w; s < se; s += 4) {
    const float* cr = ctx + ((size_t)b*S_ + s)*H_ + lane*8;
    float4 cA = *(const float4*)cr;
    float4 cB = *(const float4*)(cr + 4);
    float d = cA.x*hA.x + cA.y*hA.y + cA.z*hA.z + cA.w*hA.w
            + cB.x*hB.x + cB.y*hB.y + cB.z*hB.z + cB.w*hB.w;
    d = wred(d);
    float sc = d + bias[s];
    if (lane == 0) scw[s] = sc;
    float mn = fmaxf(m, sc);
    float al = (mn == m) ? 1.f : __expf(m - mn);
    float wg = (sc == NEG_INF) ? 0.f : __expf(sc - mn);
    l = l*al + wg;
    a0 = a0*al + wg*cA.x; a1 = a1*al + wg*cA.y;
    a2 = a2*al + wg*cA.z; a3 = a3*al + wg*cA.w;
    a4 = a4*al + wg*cB.x; a5 = a5*al + wg*cB.y;
    a6 = a6*al + wg*cB.z; a7 = a7*al + wg*cB.w;
    m = mn;
  }
  if (lane == 0) { s_ml[w*2] = m; s_ml[w*2+1] = l; }
  { float* r = s_red[w] + lane*8;
    r[0]=a0; r[1]=a1; r[2]=a2; r[3]=a3; r[4]=a4; r[5]=a5; r[6]=a6; r[7]=a7; }
  __syncthreads();
  float m0=s_ml[0], l0=s_ml[1], m1=s_ml[2], l1=s_ml[3],
        m2=s_ml[4], l2=s_ml[5], m3=s_ml[6], l3=s_ml[7];
  float mb = fmaxf(fmaxf(m0,m1), fmaxf(m2,m3));
  float k0 = (l0>0.f) ? __expf(m0-mb) : 0.f;
  float k1 = (l1>0.f) ? __expf(m1-mb) : 0.f;
  float k2 = (l2>0.f) ? __expf(m2-mb) : 0.f;
  float k3 = (l3>0.f) ? __expf(m3-mb) : 0.f;
  float lb = k0*l0 + k1*l1 + k2*l2 + k3*l3;
  float* Pp = F + F_PART + (size_t)(t&1)*(B_*NCH*PSTR) + (size_t)(b*NCH+ch)*PSTR;
  for (int u = tid; u < H_; u += BLK)
    Pp[8+u] = k0*s_red[0][u] + k1*s_red[1][u] + k2*s_red[2][u] + k3*s_red[3][u];
  if (tid == 0) { Pp[0] = mb; Pp[1] = lb; }
}

// ---------------- Phase C: outputs for step tc ----------------
// blocks [0,ABLK): (b = bid>>1, p = bid&1). Merge partials -> attn_ctx; write
// attn_dist, out row slice, p_gen.
__device__ void do_C(int tc, int bid, int tid,
                     const float* __restrict__ emb, const float* __restrict__ Wout,
                     const float* __restrict__ bout, const float* __restrict__ Wpg,
                     float* __restrict__ out, float* __restrict__ F,
                     float* s_actx, float* s_tmp)
{
  const int b = bid >> 1, p = bid & 1;
  const float* P0 = F + F_PART + (size_t)(tc&1)*(B_*NCH*PSTR) + (size_t)(b*NCH)*PSTR;
  float mk[NCH], lk[NCH], ck[NCH];
  float mb = NEG_INF;
#pragma unroll
  for (int k = 0; k < NCH; ++k) { mk[k]=P0[k*PSTR]; lk[k]=P0[k*PSTR+1]; mb=fmaxf(mb,mk[k]); }
  float lb = 0.f;
#pragma unroll
  for (int k = 0; k < NCH; ++k) { ck[k] = (lk[k]>0.f) ? __expf(mk[k]-mb) : 0.f; lb += ck[k]*lk[k]; }
  float inv = 1.f/lb;
  for (int u = tid; u < H_; u += BLK) {
    float v = 0.f;
#pragma unroll
    for (int k = 0; k < NCH; ++k) v += ck[k]*P0[k*PSTR+8+u];
    s_actx[u] = v*inv;
  }
  __syncthreads();
  { // attention distribution
    const float* scr = F + F_SC2 + (size_t)(tc&1)*(B_*S_) + b*S_;
    float* ad = out + O_AD + ((size_t)tc*B_ + b)*S_;
    int s = p*512 + tid;
    ad[s] = __expf(scr[s]-mb)*inv;
    s += 256;
    ad[s] = __expf(scr[s]-mb)*inv;
  }
  const float* hb = F + F_H3 + (tc%3)*(B_*H_) + b*H_;
  { // out = [attn_ctx, h] @ W_out + b_out
    int j = p*256 + tid;
    float acc = bout[j];
    const float* wq = Wout + j;
    for (int k = 0; k < H_; ++k) { acc = fmaf(s_actx[k], wq[0], acc); wq += H_; }
    for (int k = 0; k < H_; ++k) { acc = fmaf(hb[k],     wq[0], acc); wq += H_; }
    out[O_OUT + ((size_t)tc*B_ + b)*H_ + j] = acc;
  }
  if (p == 0) { // p_gen via folded dot products
    const float* cb = F + F_C3 + (tc%3)*(B_*H_) + b*H_;
    const float* xr = emb + ((size_t)b*T_ + tc)*E_;
    float part = 0.f;
    for (int i = tid; i < 1792; i += BLK) {
      float v;
      if (i < 512)       v = s_actx[i]   * F[F_V1 + i];
      else if (i < 1024) v = hb[i-512]   * Wpg[i];
      else if (i < 1536) v = cb[i-1024]  * Wpg[i];
      else               v = xr[i-1536]  * F[F_VX + i - 1536];
      part += v;
    }
    part = wred(part);
    if ((tid & 63) == 0) s_tmp[tid>>6] = part;
    __syncthreads();
    if (tid == 0)
      out[O_PG + (size_t)tc*B_ + b] = sigm(s_tmp[0]+s_tmp[1]+s_tmp[2]+s_tmp[3] + F[F_S0]);
  }
}

__global__ __launch_bounds__(BLK, 2)
void decoder_kernel(const float* __restrict__ emb, const float* __restrict__ h0,
                    const float* __restrict__ c0, const float* __restrict__ ctx,
                    const float* __restrict__ Wih, const float* __restrict__ bih,
                    const float* __restrict__ Whh, const float* __restrict__ bhh,
                    const float* __restrict__ Wout, const float* __restrict__ bout,
                    const float* __restrict__ Wax, const float* __restrict__ bax,
                    const float* __restrict__ Wpg, const float* __restrict__ bpg,
                    float* __restrict__ out, float* __restrict__ F)
{
  __shared__ float s_red[4][H_+8];
  __shared__ float s_ml[8];
  __shared__ float s_actx[H_];
  __shared__ float s_tmp[4];
  unsigned* W = (unsigned*)F;
  const int tid = threadIdx.x, bid = blockIdx.x;
  unsigned ep = 0;

  // ---- phase 0: init state, mask bias, p_gen folds ----
  { int i = bid*BLK + tid;
    if (i < B_*H_) { F[F_H3 + 2*(B_*H_) + i] = h0[i]; F[F_C3 + 2*(B_*H_) + i] = c0[i]; } }
  { const int w = tid>>6, lane = tid&63;
    for (int rr = 0; rr < 32; ++rr) {
      int row = bid*128 + rr*4 + w;                       // row = b*S + s
      const float* cr = ctx + (size_t)row*H_ + lane*8;
      float4 cA = *(const float4*)cr, cB = *(const float4*)(cr+4);
      float ssum = cA.x+cA.y+cA.z+cA.w+cB.x+cB.y+cB.z+cB.w;
      ssum = wred(ssum);
      if (lane == 0) F[F_BIAS + row] = (ssum == 0.f) ? NEG_INF : 0.f;
    } }
  if (bid < 5) {
    const int w = tid>>6, lane = tid&63;
    const float* wp = Wpg + 1536 + lane*8;
    float4 wA = *(const float4*)wp, wB = *(const float4*)(wp+4);
    if (bid < 4) {
      for (int rr = 0; rr < 32; ++rr) {
        int k = bid*128 + rr*4 + w;
        const float* ar = Wax + (size_t)k*H_ + lane*8;
        float4 xA = *(const float4*)ar, xB = *(const float4*)(ar+4);
        float d = xA.x*wA.x+xA.y*wA.y+xA.z*wA.z+xA.w*wA.w
                + xB.x*wB.x+xB.y*wB.y+xB.z*wB.z+xB.w*wB.w;
        d = wred(d);
        if (lane == 0) F[F_V1 + k] = Wpg[k] + d;
      }
    } else {
      for (int rr = 0; rr < 64; ++rr) {
        int k = rr*4 + w;
        const float* ar = Wax + (size_t)(512+k)*H_ + lane*8;
        float4 xA = *(const float4*)ar, xB = *(const float4*)(ar+4);
        float d = xA.x*wA.x+xA.y*wA.y+xA.z*wA.z+xA.w*wA.w
                + xB.x*wB.x+xB.y*wB.y+xB.z*wB.z+xB.w*wB.w;
        d = wred(d);
        if (lane == 0) F[F_VX + k] = d;
      }
      if (tid < 64) {
        const float* br = bax + lane*8;
        float4 bA = *(const float4*)br, bB = *(const float4*)(br+4);
        float d = bA.x*wA.x+bA.y*wA.y+bA.z*wA.z+bA.w*wA.w
                + bB.x*wB.x+bB.y*wB.y+bB.z*wB.z+bB.w*wB.w;
        d = wred(d);
        if (lane == 0) F[F_S0] = bpg[0] + d;
      }
    }
  }
  gbar(W, ++ep);

  // ---- prologue: A_0 ----
  if (bid < ABLK) do_A(0, bid, tid, emb, Wih, bih, Whh, bhh, F);
  gbar(W, ++ep);

  // ---- main loop: one barrier per step; B_t || A_{t+1} || C_{t-1} ----
  for (int t = 0; t < T_; ++t) {
    if (bid >= ABLK) {
      do_B(t, bid, tid, ctx, F, s_red, s_ml);
    } else {
      if (t < T_-1) do_A(t+1, bid, tid, emb, Wih, bih, Whh, bhh, F);
      if (t > 0)    do_C(t-1, bid, tid, emb, Wout, bout, Wpg, out, F, s_actx, s_tmp);
    }
    gbar(W, ++ep);
  }

  // ---- epilogue: C_{T-1} + final h,c  (h_127 lives in slot 127%3 == 1) ----
  if (bid < ABLK) {
    do_C(T_-1, bid, tid, emb, Wout, bout, Wpg, out, F, s_actx, s_tmp);
  } else {
    for (int i = (bid-ABLK)*BLK + tid; i < B_*H_; i += (NBLK-ABLK)*BLK) {
      out[O_H + i] = F[F_H3 + 1*(B_*H_) + i];
      out[O_C + i] = F[F_C3 + 1*(B_*H_) + i];
    }
  }
}

extern "C" void kernel_launch(void* const* d_in, const int* in_sizes, int n_in,
                              void* d_out, int out_size, void* d_ws, size_t ws_size,
                              hipStream_t stream)
{
  if (ws_size < (size_t)F_TOTAL * sizeof(float)) return;  // loud failure, no corruption
  hipMemsetAsync(d_ws, 0, U_TOTAL * sizeof(unsigned), stream);  // reset barrier flags
  decoder_kernel<<<dim3(NBLK), dim3(BLK), 0, stream>>>(
      (const float*)d_in[0],  (const float*)d_in[1],  (const float*)d_in[2],
      (const float*)d_in[3],  (const float*)d_in[4],  (const float*)d_in[5],
      (const float*)d_in[6],  (const float*)d_in[7],  (const float*)d_in[8],
      (const float*)d_in[9],  (const float*)d_in[10], (const float*)d_in[11],
      (const float*)d_in[12], (const float*)d_in[13],
      (float*)d_out, (float*)d_ws);
}

// Round 3
// 13941.844 us; speedup vs baseline: 6.4082x; 1.2285x over previous
//
#include <hip/hip_runtime.h>

// Problem dims
#define T_ 128
#define B_ 64
#define E_ 256
#define H_ 512
#define S_ 1024
#define G_ 2048           // 4H
#define NCH 6             // attention s-chunks per batch row
#define NBLK 512
#define ABLK 128          // blocks doing LSTM (A) + output heads (C)
#define BLK 256
#define NGRP 8            // broadcast "go" lines
#define MAXCH 172         // max rows per attention chunk (ceil(1024/6)=171)

// ---- barrier area (uint indices into ws) ----
#define U_ARR   128
#define U_TOTAL (U_ARR + NBLK*16)          // 8320 uints = 33280 B

// ws layout (float indices)
#define F_V1   8704                     // 512: Wpg[0:512] + Wax_top @ w4
#define F_VX   (F_V1 + H_)              // 256: Wax_bot @ w4   (contiguous after V1)
#define F_S0   (F_VX + E_)              // 1:   b_pg + b_ax . w4
#define F_H3   (F_S0 + 64)              // 3 * B*H  (h_t at slot t%3; h0 at slot 2)
#define F_C3   (F_H3 + 3*B_*H_)
#define F_SC2  (F_C3 + 3*B_*H_)         // 2 * B*S raw scores (double buffer)
#define PSTR   520
#define F_PART (F_SC2 + 2*B_*S_)        // 2 * B*NCH*PSTR partials {m,l,pad,ctx[512]}
#define F_TOTAL (F_PART + 2*B_*NCH*PSTR)

// out layout (float indices)
#define O_OUT 0
#define O_H   ((size_t)T_*B_*H_)
#define O_C   (O_H + B_*H_)
#define O_AD  (O_C + B_*H_)
#define O_PG  (O_AD + (size_t)T_*B_*S_)

#define NEG_INF (-__builtin_inff())

__device__ __forceinline__ float sigm(float x){ return 1.f/(1.f+__expf(-x)); }
__device__ __forceinline__ float tanh_(float x){ return 1.f - 2.f/(1.f+__expf(2.f*x)); }
__device__ __forceinline__ float wred(float v){
#pragma unroll
  for (int m = 1; m < 64; m <<= 1) v += __shfl_xor(v, m, 64);
  return v;
}
// device-coherent (sc1) scalar access — no cache flush/invalidate needed
__device__ __forceinline__ float ald(const float* p){
  return __hip_atomic_load(p, __ATOMIC_RELAXED, __HIP_MEMORY_SCOPE_AGENT);
}
__device__ __forceinline__ void ast(float* p, float v){
  __hip_atomic_store(p, v, __ATOMIC_RELAXED, __HIP_MEMORY_SCOPE_AGENT);
}

// ---- fence-free grid barrier ----
// data is communicated via sc1 atomics (coherent at L3), so the barrier needs
// NO agent fences -> L1/L2 stay warm across steps. syncthreads drains each
// wave's vmcnt before s_barrier; explicit vmcnt(0) covers tid0's own stores.
__device__ __forceinline__ void gbar(unsigned* W, unsigned ep){
  __syncthreads();
  const int tid = threadIdx.x, bid = blockIdx.x;
  if (tid == 0) {
    asm volatile("s_waitcnt vmcnt(0)" ::: "memory");
    __hip_atomic_store(&W[U_ARR + bid*16], ep, __ATOMIC_RELAXED, __HIP_MEMORY_SCOPE_AGENT);
  }
  if (bid == 0) {
    const int i0 = tid*2, i1 = i0+1;
    while (__hip_atomic_load(&W[U_ARR + i0*16], __ATOMIC_RELAXED, __HIP_MEMORY_SCOPE_AGENT) < ep)
      __builtin_amdgcn_s_sleep(1);
    while (__hip_atomic_load(&W[U_ARR + i1*16], __ATOMIC_RELAXED, __HIP_MEMORY_SCOPE_AGENT) < ep)
      __builtin_amdgcn_s_sleep(1);
    __syncthreads();
    if (tid < NGRP)
      __hip_atomic_store(&W[tid*16], ep, __ATOMIC_RELAXED, __HIP_MEMORY_SCOPE_AGENT);
  }
  if (tid == 0) {
    while (__hip_atomic_load(&W[(bid>>6)*16], __ATOMIC_RELAXED, __HIP_MEMORY_SCOPE_AGENT) < ep)
      __builtin_amdgcn_s_sleep(2);
  }
  __syncthreads();
}

// ---------------- Phase A: LSTM cell for step t ----------------
// 128 blocks = 16 batch-groups x 8 unit-groups. bid&7 = unit-group = XCD ->
// the 16 blocks sharing a 768KB weight slice sit on one XCD (L2-resident).
// thread = (batch bl, gate g, unit-quad q): float4 coalesced weight loads.
__device__ void do_A(int t, int bid, int tid,
                     const float* __restrict__ emb, const float* __restrict__ Wih,
                     const float* __restrict__ bih, const float* __restrict__ Whh,
                     const float* __restrict__ bhh, float* __restrict__ F,
                     float (*s_h)[H_], float (*s_gate)[4][68])
{
  const int bg = bid >> 3, ug = bid & 7;
  {  // stage h_{t-1}[bg*4 .. bg*4+3][:] into LDS (2048 sc1 loads, pipelined)
    const float* hsrc = F + F_H3 + ((t+2)%3)*(B_*H_) + (size_t)(bg*4)*H_;
#pragma unroll
    for (int j = 0; j < 8; ++j) {
      int idx = tid + j*BLK;
      s_h[idx>>9][idx&511] = ald(hsrc + idx);
    }
  }
  __syncthreads();
  const int bl = tid >> 6, g = (tid >> 4) & 3, q = tid & 15;
  const int b = bg*4 + bl, u = ug*64 + q*4;
  float4 acc;
  { const float4 b1 = *(const float4*)(bih + g*512 + u);
    const float4 b2 = *(const float4*)(bhh + g*512 + u);
    acc.x = b1.x+b2.x; acc.y = b1.y+b2.y; acc.z = b1.z+b2.z; acc.w = b1.w+b2.w; }
  const float* xr = emb + ((size_t)b*T_ + t)*E_;     // emb is [B,T,E]
  const float* wp = Wih + g*512 + u;
#pragma unroll 4
  for (int k = 0; k < E_; ++k) {
    float xv = xr[k];
    float4 wv = *(const float4*)wp;
    acc.x = fmaf(xv, wv.x, acc.x); acc.y = fmaf(xv, wv.y, acc.y);
    acc.z = fmaf(xv, wv.z, acc.z); acc.w = fmaf(xv, wv.w, acc.w);
    wp += G_;
  }
  wp = Whh + g*512 + u;
#pragma unroll 4
  for (int k = 0; k < H_; ++k) {
    float hv = s_h[bl][k];
    float4 wv = *(const float4*)wp;
    acc.x = fmaf(hv, wv.x, acc.x); acc.y = fmaf(hv, wv.y, acc.y);
    acc.z = fmaf(hv, wv.z, acc.z); acc.w = fmaf(hv, wv.w, acc.w);
    wp += G_;
  }
  { float* gq = &s_gate[bl][g][q*4];
    gq[0]=acc.x; gq[1]=acc.y; gq[2]=acc.z; gq[3]=acc.w; }
  __syncthreads();
  // gate combine: thread -> (bl2, u2)
  const int bl2 = tid >> 6, u2 = tid & 63;
  const int b2 = bg*4 + bl2, uu = ug*64 + u2;
  float gi = s_gate[bl2][0][u2], gf = s_gate[bl2][1][u2],
        gg = s_gate[bl2][2][u2], go = s_gate[bl2][3][u2];
  float cp = ald(F + F_C3 + ((t+2)%3)*(B_*H_) + (size_t)b2*H_ + uu);
  float cn = sigm(gf)*cp + sigm(gi)*tanh_(gg);
  float hn = sigm(go)*tanh_(cn);
  ast(F + F_H3 + (t%3)*(B_*H_) + (size_t)b2*H_ + uu, hn);
  ast(F + F_C3 + (t%3)*(B_*H_) + (size_t)b2*H_ + uu, cn);
}

// ---------------- Phase B: single-pass attention partials for step t ----------------
// blocks [ABLK,NBLK): block owns (b, chunk). 4-row batches: 4 interleaved
// shfl-reduce chains (ILP), one online-softmax rescale per batch.
__device__ void do_B(int t, int bid, int tid, const float* __restrict__ ctx,
                     float* __restrict__ F, float (*s_red)[H_+8], float* s_ml,
                     const float* s_bias)
{
  const int idx = bid - ABLK;
  const int b = idx / NCH, ch = idx - b*NCH;
  const int sb = (ch*S_)/NCH, se = ((ch+1)*S_)/NCH;
  const int w = tid >> 6, lane = tid & 63;
  const float* hb = F + F_H3 + (t%3)*(B_*H_) + (size_t)b*H_ + lane*8;
  float h0_=ald(hb+0), h1_=ald(hb+1), h2_=ald(hb+2), h3_=ald(hb+3),
        h4_=ald(hb+4), h5_=ald(hb+5), h6_=ald(hb+6), h7_=ald(hb+7);
  float* scw = F + F_SC2 + (size_t)(t&1)*(B_*S_) + (size_t)b*S_;
  const float* cbase = ctx + (size_t)b*S_*H_ + lane*8;
  float m = NEG_INF, l = 0.f;
  float a0=0,a1=0,a2=0,a3=0,a4=0,a5=0,a6=0,a7=0;
  for (int s0 = sb + w*4; s0 < se; s0 += 16) {
    float4 cA[4], cB[4]; float d[4];
#pragma unroll
    for (int i = 0; i < 4; ++i) {
      int s = s0 + i;
      const float* cr = cbase + (size_t)(s < se ? s : sb)*H_;
      cA[i] = *(const float4*)cr; cB[i] = *(const float4*)(cr + 4);
      d[i] = cA[i].x*h0_ + cA[i].y*h1_ + cA[i].z*h2_ + cA[i].w*h3_
           + cB[i].x*h4_ + cB[i].y*h5_ + cB[i].z*h6_ + cB[i].w*h7_;
    }
#pragma unroll
    for (int mm = 1; mm < 64; mm <<= 1) {   // 4 independent chains interleave
      d[0] += __shfl_xor(d[0], mm, 64); d[1] += __shfl_xor(d[1], mm, 64);
      d[2] += __shfl_xor(d[2], mm, 64); d[3] += __shfl_xor(d[3], mm, 64);
    }
    float sc[4];
#pragma unroll
    for (int i = 0; i < 4; ++i) {
      int s = s0 + i;
      sc[i] = (s < se) ? d[i] + s_bias[s - sb] : NEG_INF;
      if (lane == 0 && s < se) ast(scw + s, sc[i]);
    }
    float mx = fmaxf(fmaxf(sc[0],sc[1]), fmaxf(sc[2],sc[3]));
    float mn = fmaxf(m, mx);
    float al = (mn == m) ? 1.f : __expf(m - mn);
    float w0 = (sc[0]==NEG_INF)?0.f:__expf(sc[0]-mn);
    float w1 = (sc[1]==NEG_INF)?0.f:__expf(sc[1]-mn);
    float w2 = (sc[2]==NEG_INF)?0.f:__expf(sc[2]-mn);
    float w3 = (sc[3]==NEG_INF)?0.f:__expf(sc[3]-mn);
    l = l*al + (w0+w1+w2+w3);
    a0 = a0*al + w0*cA[0].x + w1*cA[1].x + w2*cA[2].x + w3*cA[3].x;
    a1 = a1*al + w0*cA[0].y + w1*cA[1].y + w2*cA[2].y + w3*cA[3].y;
    a2 = a2*al + w0*cA[0].z + w1*cA[1].z + w2*cA[2].z + w3*cA[3].z;
    a3 = a3*al + w0*cA[0].w + w1*cA[1].w + w2*cA[2].w + w3*cA[3].w;
    a4 = a4*al + w0*cB[0].x + w1*cB[1].x + w2*cB[2].x + w3*cB[3].x;
    a5 = a5*al + w0*cB[0].y + w1*cB[1].y + w2*cB[2].y + w3*cB[3].y;
    a6 = a6*al + w0*cB[0].z + w1*cB[1].z + w2*cB[2].z + w3*cB[3].z;
    a7 = a7*al + w0*cB[0].w + w1*cB[1].w + w2*cB[2].w + w3*cB[3].w;
    m = mn;
  }
  if (lane == 0) { s_ml[w*2] = m; s_ml[w*2+1] = l; }
  { float* r = s_red[w] + lane*8;
    r[0]=a0; r[1]=a1; r[2]=a2; r[3]=a3; r[4]=a4; r[5]=a5; r[6]=a6; r[7]=a7; }
  __syncthreads();
  float m0=s_ml[0], l0=s_ml[1], m1=s_ml[2], l1=s_ml[3],
        m2=s_ml[4], l2=s_ml[5], m3=s_ml[6], l3=s_ml[7];
  float mb = fmaxf(fmaxf(m0,m1), fmaxf(m2,m3));
  float k0 = (l0>0.f) ? __expf(m0-mb) : 0.f;
  float k1 = (l1>0.f) ? __expf(m1-mb) : 0.f;
  float k2 = (l2>0.f) ? __expf(m2-mb) : 0.f;
  float k3 = (l3>0.f) ? __expf(m3-mb) : 0.f;
  float lb = k0*l0 + k1*l1 + k2*l2 + k3*l3;
  float* Pp = F + F_PART + (size_t)(t&1)*(B_*NCH*PSTR) + (size_t)(b*NCH+ch)*PSTR;
  for (int u = tid; u < H_; u += BLK)
    ast(Pp + 8 + u, k0*s_red[0][u] + k1*s_red[1][u] + k2*s_red[2][u] + k3*s_red[3][u]);
  if (tid == 0) { ast(Pp+0, mb); ast(Pp+1, lb); }
}

// ---------------- Phase C: outputs for step tc ----------------
__device__ void do_C(int tc, int bid, int tid,
                     const float* __restrict__ emb, const float* __restrict__ Wout,
                     const float* __restrict__ bout, const float* __restrict__ Wpg,
                     float* __restrict__ out, float* __restrict__ F,
                     float* s_actx, float* s_tmp, float* s_hC,
                     const float* s_V1, const float* s_VX, const float* s_S0)
{
  const int b = bid >> 1, p = bid & 1;
  const float* hsrc = F + F_H3 + (tc%3)*(B_*H_) + (size_t)b*H_;
  s_hC[tid]     = ald(hsrc + tid);          // stage h_{tc} into LDS
  s_hC[tid+256] = ald(hsrc + tid + 256);
  const float* P0 = F + F_PART + (size_t)(tc&1)*(B_*NCH*PSTR) + (size_t)(b*NCH)*PSTR;
  float mk[NCH], lk[NCH], ck[NCH];
  float mb = NEG_INF;
#pragma unroll
  for (int k = 0; k < NCH; ++k) { mk[k]=ald(P0+k*PSTR); lk[k]=ald(P0+k*PSTR+1); mb=fmaxf(mb,mk[k]); }
  float lb = 0.f;
#pragma unroll
  for (int k = 0; k < NCH; ++k) { ck[k] = (lk[k]>0.f) ? __expf(mk[k]-mb) : 0.f; lb += ck[k]*lk[k]; }
  float inv = 1.f/lb;
  for (int u = tid; u < H_; u += BLK) {
    float v = 0.f;
#pragma unroll
    for (int k = 0; k < NCH; ++k) v += ck[k]*ald(P0 + k*PSTR + 8 + u);
    s_actx[u] = v*inv;
  }
  __syncthreads();
  { // attention distribution
    const float* scr = F + F_SC2 + (size_t)(tc&1)*(B_*S_) + (size_t)b*S_;
    float* ad = out + O_AD + ((size_t)tc*B_ + b)*S_;
    int s = p*512 + tid;
    ad[s] = __expf(ald(scr+s)-mb)*inv;
    s += 256;
    ad[s] = __expf(ald(scr+s)-mb)*inv;
  }
  { // out = [attn_ctx, h] @ W_out + b_out
    int j = p*256 + tid;
    float acc = bout[j];
    const float* wq = Wout + j;
    for (int k = 0; k < H_; ++k) { acc = fmaf(s_actx[k], wq[0], acc); wq += H_; }
    for (int k = 0; k < H_; ++k) { acc = fmaf(s_hC[k],   wq[0], acc); wq += H_; }
    out[O_OUT + ((size_t)tc*B_ + b)*H_ + j] = acc;
  }
  if (p == 0) { // p_gen via folded dot products
    const float* cb = F + F_C3 + (tc%3)*(B_*H_) + (size_t)b*H_;
    const float* xr = emb + ((size_t)b*T_ + tc)*E_;
    float part = 0.f;
    for (int i = tid; i < 1792; i += BLK) {
      float v;
      if (i < 512)       v = s_actx[i]     * s_V1[i];
      else if (i < 1024) v = s_hC[i-512]   * Wpg[i];
      else if (i < 1536) v = ald(cb+i-1024)* Wpg[i];
      else               v = xr[i-1536]    * s_VX[i-1536];
      part += v;
    }
    part = wred(part);
    if ((tid & 63) == 0) s_tmp[tid>>6] = part;
    __syncthreads();
    if (tid == 0)
      out[O_PG + (size_t)tc*B_ + b] = sigm(s_tmp[0]+s_tmp[1]+s_tmp[2]+s_tmp[3] + s_S0[0]);
  }
}

__global__ __launch_bounds__(BLK, 2)
void decoder_kernel(const float* __restrict__ emb, const float* __restrict__ h0,
                    const float* __restrict__ c0, const float* __restrict__ ctx,
                    const float* __restrict__ Wih, const float* __restrict__ bih,
                    const float* __restrict__ Whh, const float* __restrict__ bhh,
                    const float* __restrict__ Wout, const float* __restrict__ bout,
                    const float* __restrict__ Wax, const float* __restrict__ bax,
                    const float* __restrict__ Wpg, const float* __restrict__ bpg,
                    float* __restrict__ out, float* __restrict__ F)
{
  __shared__ float s_red[4][H_+8];
  __shared__ float s_ml[8];
  __shared__ float s_actx[H_];
  __shared__ float s_tmp[4];
  __shared__ float s_bias[MAXCH];
  __shared__ float s_h[4][H_];
  __shared__ float s_gate[4][4][68];
  __shared__ float s_hC[H_];
  __shared__ float s_V1[H_];
  __shared__ float s_VX[E_];
  __shared__ float s_S0[1];
  unsigned* W = (unsigned*)F;
  const int tid = threadIdx.x, bid = blockIdx.x;
  unsigned ep = 0;

  // ---- phase 0 ----
  if (bid < ABLK) {            // init h/c slot 2 from h0,c0
    int i = bid*BLK + tid;
    ast(F + F_H3 + 2*(B_*H_) + i, h0[i]);
    ast(F + F_C3 + 2*(B_*H_) + i, c0[i]);
  } else {                     // B-blocks: block-local mask bias into LDS
    const int idx = bid - ABLK;
    const int b = idx / NCH, ch = idx - b*NCH;
    const int sb = (ch*S_)/NCH, se = ((ch+1)*S_)/NCH;
    const int w = tid >> 6, lane = tid & 63;
    for (int s = sb + w; s < se; s += 4) {
      const float* cr = ctx + ((size_t)b*S_ + s)*H_ + lane*8;
      float4 cA = *(const float4*)cr, cB = *(const float4*)(cr+4);
      float ssum = cA.x+cA.y+cA.z+cA.w+cB.x+cB.y+cB.z+cB.w;
      ssum = wred(ssum);
      if (lane == 0) s_bias[s-sb] = (ssum == 0.f) ? NEG_INF : 0.f;
    }
  }
  if (bid < 5) {               // p_gen folds: V1, VX, S0
    const int w = tid>>6, lane = tid&63;
    const float* wp = Wpg + 1536 + lane*8;
    float4 wA = *(const float4*)wp, wB = *(const float4*)(wp+4);
    if (bid < 4) {
      for (int rr = 0; rr < 32; ++rr) {
        int k = bid*128 + rr*4 + w;
        const float* ar = Wax + (size_t)k*H_ + lane*8;
        float4 xA = *(const float4*)ar, xB = *(const float4*)(ar+4);
        float d = xA.x*wA.x+xA.y*wA.y+xA.z*wA.z+xA.w*wA.w
                + xB.x*wB.x+xB.y*wB.y+xB.z*wB.z+xB.w*wB.w;
        d = wred(d);
        if (lane == 0) ast(F + F_V1 + k, Wpg[k] + d);
      }
    } else {
      for (int rr = 0; rr < 64; ++rr) {
        int k = rr*4 + w;
        const float* ar = Wax + (size_t)(512+k)*H_ + lane*8;
        float4 xA = *(const float4*)ar, xB = *(const float4*)(ar+4);
        float d = xA.x*wA.x+xA.y*wA.y+xA.z*wA.z+xA.w*wA.w
                + xB.x*wB.x+xB.y*wB.y+xB.z*wB.z+xB.w*wB.w;
        d = wred(d);
        if (lane == 0) ast(F + F_VX + k, d);
      }
      if (tid < 64) {
        const float* br = bax + lane*8;
        float4 bA = *(const float4*)br, bB = *(const float4*)(br+4);
        float d = bA.x*wA.x+bA.y*wA.y+bA.z*wA.z+bA.w*wA.w
                + bB.x*wB.x+bB.y*wB.y+bB.z*wB.z+bB.w*wB.w;
        d = wred(d);
        if (lane == 0) ast(F + F_S0, bpg[0] + d);
      }
    }
  }
  gbar(W, ++ep);

  // stage p_gen folds into LDS once (A/C blocks only)
  if (bid < ABLK) {
    for (int i = tid; i < 769; i += BLK) {
      float v = ald(F + F_V1 + i);
      if (i < 512) s_V1[i] = v;
      else if (i < 768) s_VX[i-512] = v;
      else s_S0[0] = v;
    }
  }

  // ---- prologue: A_0 ----
  if (bid < ABLK) do_A(0, bid, tid, emb, Wih, bih, Whh, bhh, F, s_h, s_gate);
  gbar(W, ++ep);

  // ---- main loop: one barrier per step; B_t || (A_{t+1}; C_{t-1}) ----
  for (int t = 0; t < T_; ++t) {
    if (bid >= ABLK) {
      do_B(t, bid, tid, ctx, F, s_red, s_ml, s_bias);
    } else {
      if (t < T_-1) do_A(t+1, bid, tid, emb, Wih, bih, Whh, bhh, F, s_h, s_gate);
      if (t > 0)    do_C(t-1, bid, tid, emb, Wout, bout, Wpg, out, F,
                         s_actx, s_tmp, s_hC, s_V1, s_VX, s_S0);
    }
    gbar(W, ++ep);
  }

  // ---- epilogue: C_{T-1} + final h,c  (h_127 at slot 127%3 == 1) ----
  if (bid < ABLK) {
    do_C(T_-1, bid, tid, emb, Wout, bout, Wpg, out, F,
         s_actx, s_tmp, s_hC, s_V1, s_VX, s_S0);
  } else {
    for (int i = (bid-ABLK)*BLK + tid; i < B_*H_; i += (NBLK-ABLK)*BLK) {
      out[O_H + i] = ald(F + F_H3 + 1*(B_*H_) + i);
      out[O_C + i] = ald(F + F_C3 + 1*(B_*H_) + i);
    }
  }
}

extern "C" void kernel_launch(void* const* d_in, const int* in_sizes, int n_in,
                              void* d_out, int out_size, void* d_ws, size_t ws_size,
                              hipStream_t stream)
{
  if (ws_size < (size_t)F_TOTAL * sizeof(float)) return;  // loud failure, no corruption
  hipMemsetAsync(d_ws, 0, U_TOTAL * sizeof(unsigned), stream);  // reset barrier flags
  decoder_kernel<<<dim3(NBLK), dim3(BLK), 0, stream>>>(
      (const float*)d_in[0],  (const float*)d_in[1],  (const float*)d_in[2],
      (const float*)d_in[3],  (const float*)d_in[4],  (const float*)d_in[5],
      (const float*)d_in[6],  (const float*)d_in[7],  (const float*)d_in[8],
      (const float*)d_in[9],  (const float*)d_in[10], (const float*)d_in[11],
      (const float*)d_in[12], (const float*)d_in[13],
      (float*)d_out, (float*)d_ws);
}